// Round 30
// baseline (1136.484 us; speedup 1.0000x reference)
//
#include <hip/hip_runtime.h>
#include <hip/hip_bf16.h>

typedef __hip_bfloat16 bf16;
typedef short bf16x8 __attribute__((ext_vector_type(8)));   // 8 bf16 = 4 VGPRs
typedef float f32x4 __attribute__((ext_vector_type(4)));

// Problem constants
#define CB 2
#define CS 4096
#define CD 1024
#define CL 512
#define CST 64
#define CH 8
#define CT 640      // 2*ST + L
#define CDH 4096
#define NSEG 8
#define LP 80       // padded LDS row length (bf16) for attn tiles

__device__ __forceinline__ float tof(float x) { return x; }
__device__ __forceinline__ float tof(bf16 x) { return __bfloat162float(x); }
__device__ __forceinline__ void storev(float* p, float v) { *p = v; }
__device__ __forceinline__ void storev(bf16* p, float v) { *p = __float2bfloat16(v); }

__device__ __forceinline__ float ldin(const void* p, size_t i, int f32w) {
    if (f32w) return ((const float*)p)[i];
    return __bfloat162float(((const bf16*)p)[i]);
}

// async global->LDS, 16B per lane (HW: wave-uniform LDS base + lane*16)
__device__ __forceinline__ void gload16(const void* g, void* l) {
    __builtin_amdgcn_global_load_lds(
        (const __attribute__((address_space(1))) unsigned int*)g,
        (__attribute__((address_space(3))) unsigned int*)l, 16, 0, 0);
}

// ---------------------------------------------------------------------------
// Dtype sniffer (proven rounds 2/6-29; resolves flag=0 = bf16 here).
// ---------------------------------------------------------------------------
__global__ void sniff_kernel(const void* x, int* flag) {
    if (threadIdx.x == 0 && blockIdx.x == 0) {
        const bf16* hb = (const bf16*)x;
        int plaus = 0;
        for (int i = 0; i < 256; ++i) {
            float v = __bfloat162float(hb[2 * i]);
            float a = fabsf(v);
            if (v == 0.f || (a > 1e-4f && a < 100.f)) ++plaus;
        }
        flag[0] = (plaus < 128) ? 1 : 0;
    }
}

// ---------------------------------------------------------------------------
// bf16 transpose: out[C][R] = in[R][C], 64x64 tiles. PROVEN rounds 7-29.
// ---------------------------------------------------------------------------
__global__ __launch_bounds__(256) void transpose_kernel(
    const void* __restrict__ in, bf16* __restrict__ out, int R, int C,
    const int* __restrict__ flag)
{
    const int f32w = flag[0];
    __shared__ short t[64][72];
    int tid = threadIdx.x;
    int c0 = blockIdx.x * 64, r0 = blockIdx.y * 64;
    int cc = tid & 63, rr = tid >> 6;
#pragma unroll
    for (int i = 0; i < 16; ++i) {
        bf16 v = __float2bfloat16(ldin(in, (size_t)(r0 + rr + i * 4) * C + c0 + cc, f32w));
        t[rr + i * 4][cc] = *(short*)&v;
    }
    __syncthreads();
#pragma unroll
    for (int i = 0; i < 16; ++i)
        ((short*)out)[(size_t)(c0 + rr + i * 4) * R + r0 + cc] = t[cc][rr + i * 4];
}

// ---------------------------------------------------------------------------
// Merged QKV weight transpose (PROVEN rounds 21-29): 3 dispatches -> 1.
// ---------------------------------------------------------------------------
__global__ __launch_bounds__(256) void transpose3_kernel(
    const void* __restrict__ in0, const void* __restrict__ in1, const void* __restrict__ in2,
    bf16* __restrict__ out0, bf16* __restrict__ out1, bf16* __restrict__ out2,
    const int* __restrict__ flag)
{
    const int f32w = flag[0];
    const void* in = (blockIdx.z == 0) ? in0 : (blockIdx.z == 1 ? in1 : in2);
    bf16* out = (blockIdx.z == 0) ? out0 : (blockIdx.z == 1 ? out1 : out2);
    const int R = CD, C = 512;
    __shared__ short t[64][72];
    int tid = threadIdx.x;
    int c0 = blockIdx.x * 64, r0 = blockIdx.y * 64;
    int cc = tid & 63, rr = tid >> 6;
#pragma unroll
    for (int i = 0; i < 16; ++i) {
        bf16 v = __float2bfloat16(ldin(in, (size_t)(r0 + rr + i * 4) * C + c0 + cc, f32w));
        t[rr + i * 4][cc] = *(short*)&v;
    }
    __syncthreads();
#pragma unroll
    for (int i = 0; i < 16; ++i)
        ((short*)out)[(size_t)(c0 + rr + i * 4) * R + r0 + cc] = t[cc][rr + i * 4];
}

// ---------------------------------------------------------------------------
// Per-head 64x64 transpose of Wq1/Wk1/Wv1 (PROVEN rounds 15-29).
// ---------------------------------------------------------------------------
__global__ __launch_bounds__(256) void transposeH_kernel(
    const void* __restrict__ Wq1, const void* __restrict__ Wk1, const void* __restrict__ Wv1,
    bf16* __restrict__ oq, bf16* __restrict__ ok, bf16* __restrict__ ov,
    const int* __restrict__ flag)
{
    const int f32w = flag[0];
    int which = blockIdx.x >> 3, hh = blockIdx.x & 7;
    const void* in = (which == 0) ? Wq1 : (which == 1) ? Wk1 : Wv1;
    bf16* out = (which == 0) ? oq : (which == 1) ? ok : ov;
    __shared__ short t[64][72];
    int tid = threadIdx.x;
    int cc = tid & 63, rr = tid >> 6;
    size_t base = (size_t)hh * 4096;
#pragma unroll
    for (int i = 0; i < 16; ++i) {
        bf16 v = __float2bfloat16(ldin(in, base + (size_t)(rr + i * 4) * 64 + cc, f32w));
        t[rr + i * 4][cc] = *(short*)&v;
    }
    __syncthreads();
#pragma unroll
    for (int i = 0; i < 16; ++i)
        ((short*)out)[base + (size_t)(rr + i * 4) * 64 + cc] = t[cc][rr + i * 4];
}

// ---------------------------------------------------------------------------
// MFMA GEMM — THIS ROUND: global_load_lds(16B) staging, double-buffered LDS,
// one barrier per 64-K step. XOR-swizzle (rule #21 both-sides): global source
// chunk = (lane&7)^(row&7), linear LDS dest; ds_read applies the same XOR ->
// row r / chunk c lands at r*128 + (c^(r&7))*16, bank-quad (c^(r&7))%8 is a
// permutation over the 8 quads per row-octet -> conflict-free reads.
// Loads for tile t+1 issue right after the barrier and fly under MFMA(t);
// the next barrier's vmcnt(0) drain lands them (m97/m99-class schedule).
// Math bit-identical to rounds 19-29. OUTM=0: row-major C (+ACCUM).
// OUTM=2: state-only (small Wo).
// ---------------------------------------------------------------------------
template <typename TC, int ACT, int OUTM, int ACCUM>
__global__ __launch_bounds__(256) void mfma_lds(
    const bf16* __restrict__ A,
    const bf16* __restrict__ Bt0, const bf16* __restrict__ Bt1, const bf16* __restrict__ Bt2,
    TC* __restrict__ C0, TC* __restrict__ C1, TC* __restrict__ C2,
    float* __restrict__ ST,
    const void* __restrict__ bias, int boff,
    int M, int N, int K, int lda, int ldb, int seg,
    const int* __restrict__ flag)
{
    const int f32w = flag[0];
    const bf16* Bt = (blockIdx.z == 0) ? Bt0 : (blockIdx.z == 1 ? Bt1 : Bt2);
    TC* C = (blockIdx.z == 0) ? C0 : (blockIdx.z == 1 ? C1 : C2);

    __shared__ __align__(16) short As[2][128 * 64];
    __shared__ __align__(16) short Bs[2][128 * 64];

    const int tid = threadIdx.x;
    const int lane = tid & 63;
    const int w = tid >> 6;
    const int wm = w >> 1, wn = w & 1;
    const int bm = blockIdx.x * 128, bn = blockIdx.y * 128;
    const int ldsb = w * 2048;              // wave-uniform LDS base (shorts)

    f32x4 acc[4][4];
#pragma unroll
    for (int i = 0; i < 4; ++i)
#pragma unroll
        for (int j = 0; j < 4; ++j) acc[i][j] = (f32x4){0.f, 0.f, 0.f, 0.f};

    // load descriptors: instruction i covers rows w*32+i*8 .. +8, this lane's
    // row = +lane>>3; source col chunk pre-swizzled so linear LDS + swizzled
    // read compose to identity.
    int lr[4], lcq[4];
#pragma unroll
    for (int i = 0; i < 4; ++i) {
        int r = w * 32 + i * 8 + (lane >> 3);
        lr[i] = r;
        lcq[i] = ((lane & 7) ^ (r & 7)) * 8;
    }

    const int nt = K >> 6;
    // prologue: tile 0 -> buffer 0
#pragma unroll
    for (int i = 0; i < 4; ++i) {
        gload16(A + (size_t)(bm + lr[i]) * lda + lcq[i], &As[0][ldsb + i * 512]);
        gload16(Bt + (size_t)(bn + lr[i]) * ldb + lcq[i], &Bs[0][ldsb + i * 512]);
    }

    for (int t = 0; t < nt; ++t) {
        __syncthreads();   // drains vmcnt(0): tile-t loads visible to all waves
        if (t + 1 < nt) {
            const int kn = (t + 1) << 6;
            const int nb = (t + 1) & 1;
#pragma unroll
            for (int i = 0; i < 4; ++i) {
                gload16(A + (size_t)(bm + lr[i]) * lda + kn + lcq[i], &As[nb][ldsb + i * 512]);
                gload16(Bt + (size_t)(bn + lr[i]) * ldb + kn + lcq[i], &Bs[nb][ldsb + i * 512]);
            }
        }
        const int cb = t & 1;
#pragma unroll
        for (int kh = 0; kh < 2; ++kh) {
            bf16x8 av[4], bv[4];
            const int cl = kh * 4 + (lane >> 4);
#pragma unroll
            for (int mi = 0; mi < 4; ++mi) {
                int r = wm * 64 + mi * 16 + (lane & 15);
                av[mi] = *(const bf16x8*)&As[cb][r * 64 + ((cl ^ (r & 7)) << 3)];
            }
#pragma unroll
            for (int nj = 0; nj < 4; ++nj) {
                int r = wn * 64 + nj * 16 + (lane & 15);
                bv[nj] = *(const bf16x8*)&Bs[cb][r * 64 + ((cl ^ (r & 7)) << 3)];
            }
#pragma unroll
            for (int mi = 0; mi < 4; ++mi)
#pragma unroll
                for (int nj = 0; nj < 4; ++nj)
                    acc[mi][nj] = __builtin_amdgcn_mfma_f32_16x16x32_bf16(
                        av[mi], bv[nj], acc[mi][nj], 0, 0, 0);
        }
    }

#pragma unroll
    for (int mi = 0; mi < 4; ++mi) {
#pragma unroll
        for (int nj = 0; nj < 4; ++nj) {
            int c = bn + wn * 64 + nj * 16 + (lane & 15);
            float bia = bias ? ldin(bias, boff + c, f32w) : 0.f;
#pragma unroll
            for (int r = 0; r < 4; ++r) {
                int row = bm + wm * 64 + mi * 16 + (lane >> 4) * 4 + r;
                float v = acc[mi][nj][r] + bia;
                if (ACT == 1) v = 0.5f * v * (1.0f + erff(v * 0.70710678118654752f));
                if (OUTM == 0) {
                    if (ACCUM) v += tof(C[(size_t)row * N + c]);
                    storev(C + (size_t)row * N + c, v);
                } else {  // OUTM == 2: small Wo -> fp32 state rows (row = b*64+t)
                    ST[(size_t)row * CD + c] = v;
                }
            }
        }
    }
}

// ---------------------------------------------------------------------------
// RoPE (in-place, bf16) on q and k + LDS-tiled transpose of v -> vt.
// PROVEN rounds 12-29.
// ---------------------------------------------------------------------------
__global__ __launch_bounds__(256) void ropeV_kernel(
    bf16* __restrict__ q, bf16* __restrict__ k,
    const bf16* __restrict__ v, bf16* __restrict__ vt)
{
    int t0 = blockIdx.x * 64, hh = blockIdx.y, b = blockIdx.z;
    int tid = threadIdx.x;
    __shared__ short lt[64][72];
    int c = tid & 63;
    int r0 = tid >> 6;
    int ip = c >> 1;
    float inv = powf(10000.f, -(float)(2 * ip) / 64.f);
#pragma unroll
    for (int i = 0; i < 16; ++i) {
        int r = r0 + i * 4;
        int t = t0 + r;
        size_t idx = ((size_t)b * CT + t) * 512 + hh * 64 + c;
        float qv = tof(q[idx]);
        float kv = tof(k[idx]);
        float ang = (float)t * inv;
        float sn, cs;
        sincosf(ang, &sn, &cs);
        float qp = __shfl_xor(qv, 1);
        float kp = __shfl_xor(kv, 1);
        float rq, rk;
        if (c & 1) { rq = qp * sn + qv * cs; rk = kp * sn + kv * cs; }
        else       { rq = qv * cs - qp * sn; rk = kv * cs - kp * sn; }
        q[idx] = __float2bfloat16(rq);
        k[idx] = __float2bfloat16(rk);
        lt[r][c] = ((const short*)v)[idx];
    }
    __syncthreads();
#pragma unroll
    for (int i = 0; i < 16; ++i) {
        int c2 = r0 + i * 4;
        int r2 = c;
        ((short*)vt)[((size_t)(b * CH + hh) * 64 + c2) * CT + t0 + r2] = lt[r2][c2];
    }
}

// ---------------------------------------------------------------------------
// MFMA flash attention (core PROVEN rounds 12-29).
// FUSE=1: grid x=10; epilogue proj1+RoPE -> q1/k1/v1t.
// FUSE=0: grid x=9; tiles 1..8 -> o1mid (batch-major), tile-9 -> o1s.
// ---------------------------------------------------------------------------
template <int FUSE>
__global__ __launch_bounds__(256) void attn_mfma(
    const bf16* __restrict__ q, const bf16* __restrict__ k, const bf16* __restrict__ vt,
    bf16* __restrict__ o,
    int qsb, int qsh, int qst,
    int ksb, int ksh, int kst,
    int seg,
    const bf16* __restrict__ Wq1t, const bf16* __restrict__ Wk1t, const bf16* __restrict__ Wv1t,
    bf16* __restrict__ q1o, bf16* __restrict__ k1o, bf16* __restrict__ v1to)
{
    const int tid = threadIdx.x;
    const int lane = tid & 63;
    const int wrow = tid >> 6;
    const int hh = blockIdx.y, b = blockIdx.z;
    const int qbase = (FUSE ? ((int)gridDim.x - 1 - (int)blockIdx.x)
                            : ((int)gridDim.x - (int)blockIdx.x)) * 64;

    __shared__ __align__(16) short Qs[64 * LP];
    __shared__ __align__(16) short Ks[64 * LP];
    __shared__ __align__(16) short Vs[64 * LP];
    __shared__ __align__(16) short Ps[64 * LP];

    const size_t qb0 = (size_t)b * qsb + (size_t)hh * qsh;
    const size_t kb0 = (size_t)b * ksb + (size_t)hh * ksh;
    const size_t vtb = (size_t)(b * CH + hh) * 64 * CT;

    int srow[2], skc[2], soff[2];
#pragma unroll
    for (int i = 0; i < 2; ++i) {
        int c = i * 256 + tid;
        srow[i] = c >> 3;
        skc[i] = c & 7;
        soff[i] = srow[i] * LP + skc[i] * 8;
    }

    bf16x8 rQ[2], rK[2], rV[2];
#pragma unroll
    for (int i = 0; i < 2; ++i) {
        rQ[i] = *(const bf16x8*)(q + qb0 + (size_t)(qbase + srow[i]) * qst + skc[i] * 8);
        rK[i] = *(const bf16x8*)(k + kb0 + (size_t)srow[i] * kst + skc[i] * 8);
        rV[i] = *(const bf16x8*)(vt + vtb + (size_t)srow[i] * CT + skc[i] * 8);
    }

    float mrow[4], lrow[4];
    f32x4 oacc[4];
#pragma unroll
    for (int r = 0; r < 4; ++r) { mrow[r] = -1e30f; lrow[r] = 0.f; }
#pragma unroll
    for (int nd = 0; nd < 4; ++nd) oacc[nd] = (f32x4){0.f, 0.f, 0.f, 0.f};

    const int ntiles = qbase / 64 + 1;
    for (int ti = 0; ti < ntiles; ++ti) {
        __syncthreads();
        if (ti == 0) {
#pragma unroll
            for (int i = 0; i < 2; ++i) *(bf16x8*)&Qs[soff[i]] = rQ[i];
        }
#pragma unroll
        for (int i = 0; i < 2; ++i) {
            *(bf16x8*)&Ks[soff[i]] = rK[i];
            *(bf16x8*)&Vs[soff[i]] = rV[i];
        }
        if (ti + 1 < ntiles) {
            int j1 = (ti + 1) * 64;
#pragma unroll
            for (int i = 0; i < 2; ++i) {
                rK[i] = *(const bf16x8*)(k + kb0 + (size_t)(j1 + srow[i]) * kst + skc[i] * 8);
                rV[i] = *(const bf16x8*)(vt + vtb + (size_t)srow[i] * CT + j1 + skc[i] * 8);
            }
        }
        __syncthreads();

        f32x4 sacc[4];
#pragma unroll
        for (int nj = 0; nj < 4; ++nj) sacc[nj] = (f32x4){0.f, 0.f, 0.f, 0.f};
#pragma unroll
        for (int kh = 0; kh < 2; ++kh) {
            int cl = kh * 4 + (lane >> 4);
            bf16x8 av = *(const bf16x8*)&Qs[(wrow * 16 + (lane & 15)) * LP + cl * 8];
#pragma unroll
            for (int nj = 0; nj < 4; ++nj) {
                bf16x8 bv = *(const bf16x8*)&Ks[(nj * 16 + (lane & 15)) * LP + cl * 8];
                sacc[nj] = __builtin_amdgcn_mfma_f32_16x16x32_bf16(av, bv, sacc[nj], 0, 0, 0);
            }
        }

        const bool diag = (ti == ntiles - 1);
        float pm[4] = {-1e30f, -1e30f, -1e30f, -1e30f};
#pragma unroll
        for (int nj = 0; nj < 4; ++nj) {
            int col_l = nj * 16 + (lane & 15);
#pragma unroll
            for (int r = 0; r < 4; ++r) {
                int row_l = wrow * 16 + ((lane >> 4) << 2) + r;
                float s = (diag && col_l > row_l) ? -1e30f : sacc[nj][r] * 0.125f;
                sacc[nj][r] = s;
                pm[r] = fmaxf(pm[r], s);
            }
        }
#pragma unroll
        for (int msk = 1; msk < 16; msk <<= 1)
#pragma unroll
            for (int r = 0; r < 4; ++r) pm[r] = fmaxf(pm[r], __shfl_xor(pm[r], msk));

        float corr[4], rs[4] = {0.f, 0.f, 0.f, 0.f};
#pragma unroll
        for (int r = 0; r < 4; ++r) {
            float mn = fmaxf(mrow[r], pm[r]);
            corr[r] = __expf(mrow[r] - mn);
            mrow[r] = mn;
        }
#pragma unroll
        for (int nj = 0; nj < 4; ++nj)
#pragma unroll
            for (int r = 0; r < 4; ++r) {
                float p = __expf(sacc[nj][r] - mrow[r]);
                sacc[nj][r] = p;
                rs[r] += p;
            }
#pragma unroll
        for (int msk = 1; msk < 16; msk <<= 1)
#pragma unroll
            for (int r = 0; r < 4; ++r) rs[r] += __shfl_xor(rs[r], msk);
#pragma unroll
        for (int r = 0; r < 4; ++r) lrow[r] = lrow[r] * corr[r] + rs[r];
#pragma unroll
        for (int nd = 0; nd < 4; ++nd)
#pragma unroll
            for (int r = 0; r < 4; ++r) oacc[nd][r] *= corr[r];

#pragma unroll
        for (int nj = 0; nj < 4; ++nj)
#pragma unroll
            for (int r = 0; r < 4; ++r) {
                bf16 pb = __float2bfloat16(sacc[nj][r]);
                Ps[(wrow * 16 + ((lane >> 4) << 2) + r) * LP + nj * 16 + (lane & 15)] =
                    *(short*)&pb;
            }

#pragma unroll
        for (int kh = 0; kh < 2; ++kh) {
            int cl = kh * 4 + (lane >> 4);
            bf16x8 pa = *(const bf16x8*)&Ps[(wrow * 16 + (lane & 15)) * LP + cl * 8];
#pragma unroll
            for (int nd = 0; nd < 4; ++nd) {
                bf16x8 bv = *(const bf16x8*)&Vs[(nd * 16 + (lane & 15)) * LP + cl * 8];
                oacc[nd] = __builtin_amdgcn_mfma_f32_16x16x32_bf16(pa, bv, oacc[nd], 0, 0, 0);
            }
        }
    }

    if (FUSE == 0) {
        // per-block-uniform destination select (tile granularity == 64)
        bf16* dst;
        int rbase;
        if (qbase == 576) { dst = q1o; rbase = b * 64 - 576; }          // o1s
        else              { dst = o;   rbase = (b * 8 + seg) * 512 - 64; }  // o1mid
#pragma unroll
        for (int nd = 0; nd < 4; ++nd) {
#pragma unroll
            for (int r = 0; r < 4; ++r) {
                int row_g = qbase + wrow * 16 + ((lane >> 4) << 2) + r;
                int col = nd * 16 + (lane & 15);
                dst[(size_t)(rbase + row_g) * 512 + hh * 64 + col] =
                    __float2bfloat16(oacc[nd][r] / lrow[r]);
            }
        }
    } else {
#pragma unroll
        for (int nd = 0; nd < 4; ++nd)
#pragma unroll
            for (int r = 0; r < 4; ++r) {
                int row_l = wrow * 16 + ((lane >> 4) << 2) + r;
                bf16 ob16 = __float2bfloat16(oacc[nd][r] / lrow[r]);
                Qs[row_l * LP + nd * 16 + (lane & 15)] = *(short*)&ob16;
            }
        __syncthreads();

        const size_t whb = (size_t)hh * 4096;
        f32x4 qa[4], ka[4], va[4];
#pragma unroll
        for (int nj = 0; nj < 4; ++nj) {
            qa[nj] = (f32x4){0.f, 0.f, 0.f, 0.f};
            ka[nj] = (f32x4){0.f, 0.f, 0.f, 0.f};
            va[nj] = (f32x4){0.f, 0.f, 0.f, 0.f};
        }
#pragma unroll
        for (int kh = 0; kh < 2; ++kh) {
            int cl = kh * 4 + (lane >> 4);
            bf16x8 av = *(const bf16x8*)&Qs[(wrow * 16 + (lane & 15)) * LP + cl * 8];
#pragma unroll
            for (int nj = 0; nj < 4; ++nj) {
                int rowb = nj * 16 + (lane & 15);
                bf16x8 bq = *(const bf16x8*)(Wq1t + whb + (size_t)rowb * 64 + cl * 8);
                bf16x8 bk = *(const bf16x8*)(Wk1t + whb + (size_t)rowb * 64 + cl * 8);
                bf16x8 bw = *(const bf16x8*)(Wv1t + whb + (size_t)rowb * 64 + cl * 8);
                qa[nj] = __builtin_amdgcn_mfma_f32_16x16x32_bf16(av, bq, qa[nj], 0, 0, 0);
                ka[nj] = __builtin_amdgcn_mfma_f32_16x16x32_bf16(av, bk, ka[nj], 0, 0, 0);
                va[nj] = __builtin_amdgcn_mfma_f32_16x16x32_bf16(av, bw, va[nj], 0, 0, 0);
            }
        }
        const size_t bh = (size_t)(b * CH + hh);
#pragma unroll
        for (int nj = 0; nj < 4; ++nj) {
            int col = nj * 16 + (lane & 15);
            int ip = col >> 1;
            float inv = powf(10000.f, -(float)(2 * ip) / 64.f);
#pragma unroll
            for (int r = 0; r < 4; ++r) {
                int row_l = wrow * 16 + ((lane >> 4) << 2) + r;
                int t = qbase + row_l;
                float ang = (float)t * inv;
                float sn, cs;
                sincosf(ang, &sn, &cs);
                float aq = qa[nj][r], ak = ka[nj][r];
                float pq = __shfl_xor(aq, 1);
                float pk = __shfl_xor(ak, 1);
                float rq, rk;
                if (col & 1) { rq = pq * sn + aq * cs; rk = pk * sn + ak * cs; }
                else         { rq = aq * cs - pq * sn; rk = ak * cs - pk * sn; }
                size_t roff = (bh * CT + t) * 64 + col;
                q1o[roff] = __float2bfloat16(rq);
                k1o[roff] = __float2bfloat16(rk);
                v1to[(bh * 64 + col) * CT + t] = __float2bfloat16(va[nj][r]);
            }
        }
    }
}

// toks = concat([state, x_seg, state]) -> bf16 (PROVEN; separate pass wins)
__global__ __launch_bounds__(256) void build_toks_kernel(
    const void* __restrict__ x, const float* __restrict__ state, bf16* __restrict__ toks,
    int seg, const int* __restrict__ flag)
{
    const int f32w = flag[0];
    int idx = blockIdx.x * 256 + threadIdx.x;  // B*T*D
    int d = idx & (CD - 1);
    int t = (idx >> 10) % CT;
    int b = idx / (CT * CD);
    float v;
    if (t < CST) v = state[(b * CST + t) * CD + d];
    else if (t < CST + CL) v = ldin(x, ((size_t)b * CS + seg * CL + (t - CST)) * CD + d, f32w);
    else v = state[(b * CST + (t - CST - CL)) * CD + d];
    toks[idx] = __float2bfloat16(v);
}

__global__ __launch_bounds__(256) void init_state_kernel(
    const void* __restrict__ s0, float* __restrict__ state, const int* __restrict__ flag)
{
    const int f32w = flag[0];
    int idx = blockIdx.x * 256 + threadIdx.x;  // B*ST*D
    state[idx] = ldin(s0, idx % (CST * CD), f32w);
}

// LayerNorm(ra + x) * g + b.  ra bf16 (PROVEN round 27).
__global__ __launch_bounds__(256) void ln_kernel(
    const bf16* __restrict__ ra, const void* __restrict__ x,
    const void* __restrict__ g, const void* __restrict__ bb,
    void* __restrict__ outp, int out_ext, const int* __restrict__ flag)
{
    const int f32w = flag[0];
    int row = blockIdx.x;
    int tid = threadIdx.x;
    __shared__ float buf[CD];
    __shared__ float red[4];

    float s = 0.f;
    for (int c = tid; c < CD; c += 256) {
        float v = tof(ra[(size_t)row * CD + c]) + ldin(x, (size_t)row * CD + c, f32w);
        buf[c] = v;
        s += v;
    }
#pragma unroll
    for (int off = 32; off; off >>= 1) s += __shfl_xor(s, off);
    if ((tid & 63) == 0) red[tid >> 6] = s;
    __syncthreads();
    float mu = (red[0] + red[1] + red[2] + red[3]) * (1.f / CD);
    __syncthreads();

    float vs = 0.f;
    for (int c = tid; c < CD; c += 256) {
        float d0 = buf[c] - mu;
        vs += d0 * d0;
    }
#pragma unroll
    for (int off = 32; off; off >>= 1) vs += __shfl_xor(vs, off);
    if ((tid & 63) == 0) red[tid >> 6] = vs;
    __syncthreads();
    float var = (red[0] + red[1] + red[2] + red[3]) * (1.f / CD);
    float rs = rsqrtf(var + 1e-5f);

    for (int c = tid; c < CD; c += 256) {
        float y = (buf[c] - mu) * rs * ldin(g, c, f32w) + ldin(bb, c, f32w);
        size_t idx = (size_t)row * CD + c;
        if (!out_ext) {
            ((bf16*)outp)[idx] = __float2bfloat16(y);
        } else if (f32w) {
            ((float*)outp)[idx] = y;
        } else {
            ((bf16*)outp)[idx] = __float2bfloat16(y);
        }
    }
}

extern "C" void kernel_launch(void* const* d_in, const int* in_sizes, int n_in,
                              void* d_out, int out_size, void* d_ws, size_t ws_size,
                              hipStream_t stream)
{
    const void* x      = d_in[0];
    const void* s0     = d_in[1];
    const void* Wq0    = d_in[2];
    const void* Wk0    = d_in[3];
    const void* Wv0    = d_in[4];
    const void* Wq1    = d_in[5];
    const void* Wk1    = d_in[6];
    const void* Wv1    = d_in[7];
    const void* Wo     = d_in[8];
    const void* bo     = d_in[9];
    const void* g_attn = d_in[10];
    const void* b_attn = d_in[11];
    const void* W1     = d_in[12];
    const void* b1     = d_in[13];
    const void* W2     = d_in[14];
    const void* b2     = d_in[15];
    const void* g_mlp  = d_in[16];
    const void* b_mlp  = d_in[17];

    // workspace slot layout BYTE-IDENTICAL to passing rounds 2/6-29 (~90.7 MB)
    int* flag = (int*)d_ws;
    float* f = (float*)((char*)d_ws + 16);
    float* toks_slot = f; f += (size_t)CB * CT * CD;       // bf16 toks
    float* q0_slot = f;  f += (size_t)CB * CH * CT * 64;   // bf16 q0 [1280][512]
    float* k0_slot = f;  f += (size_t)CB * CH * CT * 64;   // bf16 k0
    float* v0_slot = f;  f += (size_t)CB * CH * CT * 64;   // bf16 v0
    float* o0_slot = f;  f += (size_t)CB * CH * CT * 64;   // bf16 v0t
    float* q1_slot = f;  f += (size_t)CB * CH * CT * 64;   // bf16 q1
    float* k1_slot = f;  f += (size_t)CB * CH * CT * 64;   // bf16 k1
    float* v1_slot = f;  f += (size_t)CB * CH * CT * 64;   // bf16 v1t
    float* o1t_slot = f; f += (size_t)CB * CT * (CH * 64); // (unused during segments)
    float* seg_slot = f; f += (size_t)CB * CT * CD;        // (unused during segments)
    float* state = f;   f += (size_t)CB * CST * CD;        // fp32 state
    float* a_slot = f;  f += (size_t)CB * CS * CD;         // bf16 a (half used)
    bf16* h = (bf16*)f;                                    // LN1 out [B*S, D] bf16
    bf16* tail = h + (size_t)CB * CS * CD;                 // 8.39 MB tail slot

    bf16* toks = (bf16*)toks_slot;
    bf16* q0b = (bf16*)q0_slot;
    bf16* k0b = (bf16*)k0_slot;
    bf16* v0b = (bf16*)v0_slot;
    bf16* v0t = (bf16*)o0_slot;
    bf16* q1b = (bf16*)q1_slot;
    bf16* k1b = (bf16*)k1_slot;
    bf16* v1t = (bf16*)v1_slot;
    bf16* ab  = (bf16*)a_slot;                             // [8192][1024] bf16
    bf16* WtQ = h;                                         // h region dead until LN1
    bf16* WtK = WtQ + (size_t)512 * 1024;
    bf16* WtV = WtK + (size_t)512 * 1024;
    bf16* WtO = WtV + (size_t)512 * 1024;                  // [1024][512]
    bf16* WtQ1 = WtO + (size_t)1024 * 512;                 // per-head [8][64][64]
    bf16* WtK1 = WtQ1 + (size_t)8 * 4096;
    bf16* WtV1 = WtK1 + (size_t)8 * 4096;
    // o1mid/o1s after transposed weights in h region (round-26/27-proven fit).
    bf16* o1mid = WtV1 + (size_t)8 * 4096;                 // [B*NSEG*512][512]
    bf16* o1s = o1mid + (size_t)CB * NSEG * 512 * 512;     // [128][512]
    // MLP phase (toks..q1 region dead): g1 at region base, Wt1 after, Wt2 tail.
    bf16* g1  = (bf16*)toks_slot;                          // [8192][1024] 16.78 MB
    bf16* Wt1 = g1 + (size_t)CB * CS * CD;                 // [CDH][CD]    8.39 MB
    bf16* Wt2 = tail;                                      // [CD][CDH]    8.39 MB

    sniff_kernel<<<1, 64, 0, stream>>>(x, flag);
    init_state_kernel<<<(CB * CST * CD) / 256, 256, 0, stream>>>(s0, state, flag);

    transpose3_kernel<<<dim3(8, 16, 3), 256, 0, stream>>>(
        Wq0, Wk0, Wv0, WtQ, WtK, WtV, flag);
    transpose_kernel<<<dim3(16, 8), 256, 0, stream>>>(Wo, WtO, 512, CD, flag);
    transposeH_kernel<<<24, 256, 0, stream>>>(Wq1, Wk1, Wv1, WtQ1, WtK1, WtV1, flag);
    // W2 transpose at startup (PROVEN round 28): overlaps the segment loop.
    transpose_kernel<<<dim3(CD / 64, CDH / 64), 256, 0, stream>>>(W2, Wt2, CDH, CD, flag);

    for (int seg = 0; seg < NSEG; ++seg) {
        build_toks_kernel<<<(CB * CT * CD) / 256, 256, 0, stream>>>(x, state, toks, seg, flag);
        // QKV GEMM (proven path), row-major bf16 outputs
        mfma_lds<bf16, 0, 0, 0><<<dim3(10, 4, 3), 256, 0, stream>>>(
            toks, WtQ, WtK, WtV, q0b, k0b, v0b, nullptr, nullptr, 0,
            CB * CT, 512, CD, CD, CD, 0, flag);
        // RoPE q0,k0 in place + V transpose -> v0t (proven separate pass)
        ropeV_kernel<<<dim3(CT / 64, CH, CB), 256, 0, stream>>>(q0b, k0b, v0b, v0t);
        // attn1 (row-major Q/K + v0t) with FUSED proj1+RoPE epilogue (grid 10)
        attn_mfma<1><<<dim3(CT / 64, CH, CB), 256, 0, stream>>>(
            q0b, k0b, v0t, nullptr,
            CT * 512, 64, 512,
            CT * 512, 64, 512,
            seg,
            WtQ1, WtK1, WtV1, q1b, k1b, v1t);
        // attn2 (head-major Q/K + v1t), grid 9: middle -> o1mid, tile9 -> o1s
        attn_mfma<0><<<dim3(9, CH, CB), 256, 0, stream>>>(
            q1b, k1b, v1t, o1mid,
            CH * CT * 64, CT * 64, 64,
            CH * CT * 64, CT * 64, 64,
            seg,
            nullptr, nullptr, nullptr, o1s, nullptr, nullptr);
        // small Wo: state rows only (M=128, 8 blocks) -> fp32 state
        mfma_lds<bf16, 0, 2, 0><<<dim3(1, 8, 1), 256, 0, stream>>>(
            o1s, WtO, WtO, WtO, ab, ab, ab, state, bo, 0,
            128, CD, 512, 512, 512, seg, flag);
    }

    // big Wo: all middle rows (M=8192, grid 64x8=512 blocks) -> ab (bf16) + bo
    mfma_lds<bf16, 0, 0, 0><<<dim3(64, 8, 1), 256, 0, stream>>>(
        o1mid, WtO, WtO, WtO, ab, ab, ab, nullptr, bo, 0,
        CB * CS, CD, 512, 512, 512, 0, flag);

    // h = LN(ab + x) -> bf16 internal (overwrites WtQ..o1s — dead by now)
    ln_kernel<<<CB * CS, 256, 0, stream>>>(ab, x, g_attn, b_attn, h, 0, flag);

    transpose_kernel<<<dim3(CDH / 64, CD / 64), 256, 0, stream>>>(W1, Wt1, CD, CDH, flag);

    // MLP chunked over the hidden dim (PROVEN rounds 24-29); ab is bf16
    for (int c = 0; c < 4; ++c) {
        mfma_lds<bf16, 1, 0, 0><<<dim3(64, 8, 1), 256, 0, stream>>>(
            h, Wt1 + (size_t)c * 1024 * CD, Wt1, Wt1, g1, g1, g1, nullptr,
            b1, c * 1024, CB * CS, 1024, CD, CD, CD, 0, flag);
        if (c == 0)
            mfma_lds<bf16, 0, 0, 0><<<dim3(64, 8, 1), 256, 0, stream>>>(
                g1, Wt2 + (size_t)c * 1024, Wt2, Wt2, ab, ab, ab, nullptr,
                b2, 0, CB * CS, CD, 1024, 1024, CDH, 0, flag);
        else
            mfma_lds<bf16, 0, 0, 1><<<dim3(64, 8, 1), 256, 0, stream>>>(
                g1, Wt2 + (size_t)c * 1024, Wt2, Wt2, ab, ab, ab, nullptr,
                nullptr, 0, CB * CS, CD, 1024, 1024, CDH, 0, flag);
    }
    ln_kernel<<<CB * CS, 256, 0, stream>>>(ab, x, g_mlp, b_mlp, d_out, 1, flag);
}

// Round 31
// 1071.121 us; speedup vs baseline: 1.0610x; 1.0610x over previous
//
#include <hip/hip_runtime.h>
#include <hip/hip_bf16.h>

typedef __hip_bfloat16 bf16;
typedef short bf16x8 __attribute__((ext_vector_type(8)));   // 8 bf16 = 4 VGPRs
typedef float f32x4 __attribute__((ext_vector_type(4)));

// Problem constants
#define CB 2
#define CS 4096
#define CD 1024
#define CL 512
#define CST 64
#define CH 8
#define CT 640      // 2*ST + L
#define CDH 4096
#define NSEG 8
#define LP 80       // padded LDS row length (bf16) for attn tiles
#define GP 72       // padded LDS row length (shorts) for reg-staged GEMM tiles

__device__ __forceinline__ float tof(float x) { return x; }
__device__ __forceinline__ float tof(bf16 x) { return __bfloat162float(x); }
__device__ __forceinline__ void storev(float* p, float v) { *p = v; }
__device__ __forceinline__ void storev(bf16* p, float v) { *p = __float2bfloat16(v); }

__device__ __forceinline__ float ldin(const void* p, size_t i, int f32w) {
    if (f32w) return ((const float*)p)[i];
    return __bfloat162float(((const bf16*)p)[i]);
}

// async global->LDS, 16B per lane (HW: wave-uniform LDS base + lane*16)
__device__ __forceinline__ void gload16(const void* g, void* l) {
    __builtin_amdgcn_global_load_lds(
        (const __attribute__((address_space(1))) unsigned int*)g,
        (__attribute__((address_space(3))) unsigned int*)l, 16, 0, 0);
}

// ---------------------------------------------------------------------------
// Dtype sniffer (proven rounds 2/6-30; resolves flag=0 = bf16 here).
// ---------------------------------------------------------------------------
__global__ void sniff_kernel(const void* x, int* flag) {
    if (threadIdx.x == 0 && blockIdx.x == 0) {
        const bf16* hb = (const bf16*)x;
        int plaus = 0;
        for (int i = 0; i < 256; ++i) {
            float v = __bfloat162float(hb[2 * i]);
            float a = fabsf(v);
            if (v == 0.f || (a > 1e-4f && a < 100.f)) ++plaus;
        }
        flag[0] = (plaus < 128) ? 1 : 0;
    }
}

// ---------------------------------------------------------------------------
// bf16 transpose: out[C][R] = in[R][C], 64x64 tiles. PROVEN rounds 7-30.
// ---------------------------------------------------------------------------
__global__ __launch_bounds__(256) void transpose_kernel(
    const void* __restrict__ in, bf16* __restrict__ out, int R, int C,
    const int* __restrict__ flag)
{
    const int f32w = flag[0];
    __shared__ short t[64][72];
    int tid = threadIdx.x;
    int c0 = blockIdx.x * 64, r0 = blockIdx.y * 64;
    int cc = tid & 63, rr = tid >> 6;
#pragma unroll
    for (int i = 0; i < 16; ++i) {
        bf16 v = __float2bfloat16(ldin(in, (size_t)(r0 + rr + i * 4) * C + c0 + cc, f32w));
        t[rr + i * 4][cc] = *(short*)&v;
    }
    __syncthreads();
#pragma unroll
    for (int i = 0; i < 16; ++i)
        ((short*)out)[(size_t)(c0 + rr + i * 4) * R + r0 + cc] = t[cc][rr + i * 4];
}

// ---------------------------------------------------------------------------
// Merged QKV weight transpose (PROVEN rounds 21-30): 3 dispatches -> 1.
// ---------------------------------------------------------------------------
__global__ __launch_bounds__(256) void transpose3_kernel(
    const void* __restrict__ in0, const void* __restrict__ in1, const void* __restrict__ in2,
    bf16* __restrict__ out0, bf16* __restrict__ out1, bf16* __restrict__ out2,
    const int* __restrict__ flag)
{
    const int f32w = flag[0];
    const void* in = (blockIdx.z == 0) ? in0 : (blockIdx.z == 1 ? in1 : in2);
    bf16* out = (blockIdx.z == 0) ? out0 : (blockIdx.z == 1 ? out1 : out2);
    const int R = CD, C = 512;
    __shared__ short t[64][72];
    int tid = threadIdx.x;
    int c0 = blockIdx.x * 64, r0 = blockIdx.y * 64;
    int cc = tid & 63, rr = tid >> 6;
#pragma unroll
    for (int i = 0; i < 16; ++i) {
        bf16 v = __float2bfloat16(ldin(in, (size_t)(r0 + rr + i * 4) * C + c0 + cc, f32w));
        t[rr + i * 4][cc] = *(short*)&v;
    }
    __syncthreads();
#pragma unroll
    for (int i = 0; i < 16; ++i)
        ((short*)out)[(size_t)(c0 + rr + i * 4) * R + r0 + cc] = t[cc][rr + i * 4];
}

// ---------------------------------------------------------------------------
// Per-head 64x64 transpose of Wq1/Wk1/Wv1 (PROVEN rounds 15-30).
// ---------------------------------------------------------------------------
__global__ __launch_bounds__(256) void transposeH_kernel(
    const void* __restrict__ Wq1, const void* __restrict__ Wk1, const void* __restrict__ Wv1,
    bf16* __restrict__ oq, bf16* __restrict__ ok, bf16* __restrict__ ov,
    const int* __restrict__ flag)
{
    const int f32w = flag[0];
    int which = blockIdx.x >> 3, hh = blockIdx.x & 7;
    const void* in = (which == 0) ? Wq1 : (which == 1) ? Wk1 : Wv1;
    bf16* out = (which == 0) ? oq : (which == 1) ? ok : ov;
    __shared__ short t[64][72];
    int tid = threadIdx.x;
    int cc = tid & 63, rr = tid >> 6;
    size_t base = (size_t)hh * 4096;
#pragma unroll
    for (int i = 0; i < 16; ++i) {
        bf16 v = __float2bfloat16(ldin(in, base + (size_t)(rr + i * 4) * 64 + cc, f32w));
        t[rr + i * 4][cc] = *(short*)&v;
    }
    __syncthreads();
#pragma unroll
    for (int i = 0; i < 16; ++i)
        ((short*)out)[base + (size_t)(rr + i * 4) * 64 + cc] = t[cc][rr + i * 4];
}

// ---------------------------------------------------------------------------
// mfma_reg: reg-staged GEMM, GP=72 pad, BK=64, depth-2 prefetch — the PROVEN
// round-29 1084us template, used for LOW-OCCUPANCY segment-loop dispatches
// (QKV grid 120, small-Wo grid 8) where reg-staging's cross-barrier latency
// hiding beats gload_lds (round-30 measured regression there).
// ---------------------------------------------------------------------------
template <typename TC, int ACT, int OUTM, int ACCUM>
__global__ __launch_bounds__(256) void mfma_reg(
    const bf16* __restrict__ A,
    const bf16* __restrict__ Bt0, const bf16* __restrict__ Bt1, const bf16* __restrict__ Bt2,
    TC* __restrict__ C0, TC* __restrict__ C1, TC* __restrict__ C2,
    float* __restrict__ ST,
    const void* __restrict__ bias, int boff,
    int M, int N, int K, int lda, int ldb, int seg,
    const int* __restrict__ flag)
{
    const int f32w = flag[0];
    const bf16* Bt = (blockIdx.z == 0) ? Bt0 : (blockIdx.z == 1 ? Bt1 : Bt2);
    TC* C = (blockIdx.z == 0) ? C0 : (blockIdx.z == 1 ? C1 : C2);

    __shared__ __align__(16) short As[128 * GP];
    __shared__ __align__(16) short Bs[128 * GP];

    const int tid = threadIdx.x;
    const int lane = tid & 63;
    const int w = tid >> 6;
    const int wm = w >> 1, wn = w & 1;
    const int bm = blockIdx.x * 128, bn = blockIdx.y * 128;

    f32x4 acc[4][4];
#pragma unroll
    for (int i = 0; i < 4; ++i)
#pragma unroll
        for (int j = 0; j < 4; ++j) acc[i][j] = (f32x4){0.f, 0.f, 0.f, 0.f};

    int srow[4], skc[4], soff[4];
#pragma unroll
    for (int i = 0; i < 4; ++i) {
        int c = i * 256 + tid;
        srow[i] = c >> 3;
        skc[i] = (c & 7) * 8;
        soff[i] = srow[i] * GP + skc[i];
    }

    bf16x8 rA0[4], rB0[4], rA1[4], rB1[4];
#pragma unroll
    for (int i = 0; i < 4; ++i) {
        rA0[i] = *(const bf16x8*)(A + (size_t)(bm + srow[i]) * lda + skc[i]);
        rB0[i] = *(const bf16x8*)(Bt + (size_t)(bn + srow[i]) * ldb + skc[i]);
        rA1[i] = *(const bf16x8*)(A + (size_t)(bm + srow[i]) * lda + 64 + skc[i]);
        rB1[i] = *(const bf16x8*)(Bt + (size_t)(bn + srow[i]) * ldb + 64 + skc[i]);
    }

#define MFMA_PHASE                                                              \
    _Pragma("unroll")                                                           \
    for (int kh = 0; kh < 2; ++kh) {                                            \
        bf16x8 av[4], bv[4];                                                    \
        _Pragma("unroll")                                                       \
        for (int mi = 0; mi < 4; ++mi) {                                        \
            int r = wm * 64 + mi * 16 + (lane & 15);                            \
            int cl = kh * 4 + (lane >> 4);                                      \
            av[mi] = *(const bf16x8*)&As[r * GP + cl * 8];                      \
        }                                                                       \
        _Pragma("unroll")                                                       \
        for (int nj = 0; nj < 4; ++nj) {                                        \
            int r = wn * 64 + nj * 16 + (lane & 15);                            \
            int cl = kh * 4 + (lane >> 4);                                      \
            bv[nj] = *(const bf16x8*)&Bs[r * GP + cl * 8];                      \
        }                                                                       \
        _Pragma("unroll")                                                       \
        for (int mi = 0; mi < 4; ++mi)                                          \
            _Pragma("unroll")                                                   \
            for (int nj = 0; nj < 4; ++nj)                                      \
                acc[mi][nj] = __builtin_amdgcn_mfma_f32_16x16x32_bf16(          \
                    av[mi], bv[nj], acc[mi][nj], 0, 0, 0);                      \
    }

    for (int k0 = 0; k0 < K; k0 += 128) {
        __syncthreads();
#pragma unroll
        for (int i = 0; i < 4; ++i) {
            *(bf16x8*)&As[soff[i]] = rA0[i];
            *(bf16x8*)&Bs[soff[i]] = rB0[i];
        }
        if (k0 + 128 < K) {
            int kn = k0 + 128;
#pragma unroll
            for (int i = 0; i < 4; ++i) {
                rA0[i] = *(const bf16x8*)(A + (size_t)(bm + srow[i]) * lda + kn + skc[i]);
                rB0[i] = *(const bf16x8*)(Bt + (size_t)(bn + srow[i]) * ldb + kn + skc[i]);
            }
        }
        __syncthreads();
        MFMA_PHASE

        __syncthreads();
#pragma unroll
        for (int i = 0; i < 4; ++i) {
            *(bf16x8*)&As[soff[i]] = rA1[i];
            *(bf16x8*)&Bs[soff[i]] = rB1[i];
        }
        if (k0 + 192 < K) {
            int kn = k0 + 192;
#pragma unroll
            for (int i = 0; i < 4; ++i) {
                rA1[i] = *(const bf16x8*)(A + (size_t)(bm + srow[i]) * lda + kn + skc[i]);
                rB1[i] = *(const bf16x8*)(Bt + (size_t)(bn + srow[i]) * ldb + kn + skc[i]);
            }
        }
        __syncthreads();
        MFMA_PHASE
    }
#undef MFMA_PHASE

#pragma unroll
    for (int mi = 0; mi < 4; ++mi) {
#pragma unroll
        for (int nj = 0; nj < 4; ++nj) {
            int c = bn + wn * 64 + nj * 16 + (lane & 15);
            float bia = bias ? ldin(bias, boff + c, f32w) : 0.f;
#pragma unroll
            for (int r = 0; r < 4; ++r) {
                int row = bm + wm * 64 + mi * 16 + (lane >> 4) * 4 + r;
                float v = acc[mi][nj][r] + bia;
                if (ACT == 1) v = 0.5f * v * (1.0f + erff(v * 0.70710678118654752f));
                if (OUTM == 0) {
                    if (ACCUM) v += tof(C[(size_t)row * N + c]);
                    storev(C + (size_t)row * N + c, v);
                } else {  // OUTM == 2: small Wo -> fp32 state rows (row = b*64+t)
                    ST[(size_t)row * CD + c] = v;
                }
            }
        }
    }
}

// ---------------------------------------------------------------------------
// mfma_glds: global_load_lds(16B) + XOR-swizzle, double-buffered, one barrier
// per 64-K step — the PROVEN round-30 template (bank-conflict 0, VGPR 88),
// used for HIGH-OCCUPANCY post-loop dispatches (big-Wo, MLP W1/W2, grid 512)
// where it measured 43.3 -> 39.9us vs mfma_reg.
// ---------------------------------------------------------------------------
template <typename TC, int ACT, int OUTM, int ACCUM>
__global__ __launch_bounds__(256) void mfma_glds(
    const bf16* __restrict__ A,
    const bf16* __restrict__ Bt0, const bf16* __restrict__ Bt1, const bf16* __restrict__ Bt2,
    TC* __restrict__ C0, TC* __restrict__ C1, TC* __restrict__ C2,
    float* __restrict__ ST,
    const void* __restrict__ bias, int boff,
    int M, int N, int K, int lda, int ldb, int seg,
    const int* __restrict__ flag)
{
    const int f32w = flag[0];
    const bf16* Bt = (blockIdx.z == 0) ? Bt0 : (blockIdx.z == 1 ? Bt1 : Bt2);
    TC* C = (blockIdx.z == 0) ? C0 : (blockIdx.z == 1 ? C1 : C2);

    __shared__ __align__(16) short As[2][128 * 64];
    __shared__ __align__(16) short Bs[2][128 * 64];

    const int tid = threadIdx.x;
    const int lane = tid & 63;
    const int w = tid >> 6;
    const int wm = w >> 1, wn = w & 1;
    const int bm = blockIdx.x * 128, bn = blockIdx.y * 128;
    const int ldsb = w * 2048;              // wave-uniform LDS base (shorts)

    f32x4 acc[4][4];
#pragma unroll
    for (int i = 0; i < 4; ++i)
#pragma unroll
        for (int j = 0; j < 4; ++j) acc[i][j] = (f32x4){0.f, 0.f, 0.f, 0.f};

    int lr[4], lcq[4];
#pragma unroll
    for (int i = 0; i < 4; ++i) {
        int r = w * 32 + i * 8 + (lane >> 3);
        lr[i] = r;
        lcq[i] = ((lane & 7) ^ (r & 7)) * 8;
    }

    const int nt = K >> 6;
#pragma unroll
    for (int i = 0; i < 4; ++i) {
        gload16(A + (size_t)(bm + lr[i]) * lda + lcq[i], &As[0][ldsb + i * 512]);
        gload16(Bt + (size_t)(bn + lr[i]) * ldb + lcq[i], &Bs[0][ldsb + i * 512]);
    }

    for (int t = 0; t < nt; ++t) {
        __syncthreads();   // drains vmcnt(0): tile-t loads visible to all waves
        if (t + 1 < nt) {
            const int kn = (t + 1) << 6;
            const int nb = (t + 1) & 1;
#pragma unroll
            for (int i = 0; i < 4; ++i) {
                gload16(A + (size_t)(bm + lr[i]) * lda + kn + lcq[i], &As[nb][ldsb + i * 512]);
                gload16(Bt + (size_t)(bn + lr[i]) * ldb + kn + lcq[i], &Bs[nb][ldsb + i * 512]);
            }
        }
        const int cb = t & 1;
#pragma unroll
        for (int kh = 0; kh < 2; ++kh) {
            bf16x8 av[4], bv[4];
            const int cl = kh * 4 + (lane >> 4);
#pragma unroll
            for (int mi = 0; mi < 4; ++mi) {
                int r = wm * 64 + mi * 16 + (lane & 15);
                av[mi] = *(const bf16x8*)&As[cb][r * 64 + ((cl ^ (r & 7)) << 3)];
            }
#pragma unroll
            for (int nj = 0; nj < 4; ++nj) {
                int r = wn * 64 + nj * 16 + (lane & 15);
                bv[nj] = *(const bf16x8*)&Bs[cb][r * 64 + ((cl ^ (r & 7)) << 3)];
            }
#pragma unroll
            for (int mi = 0; mi < 4; ++mi)
#pragma unroll
                for (int nj = 0; nj < 4; ++nj)
                    acc[mi][nj] = __builtin_amdgcn_mfma_f32_16x16x32_bf16(
                        av[mi], bv[nj], acc[mi][nj], 0, 0, 0);
        }
    }

#pragma unroll
    for (int mi = 0; mi < 4; ++mi) {
#pragma unroll
        for (int nj = 0; nj < 4; ++nj) {
            int c = bn + wn * 64 + nj * 16 + (lane & 15);
            float bia = bias ? ldin(bias, boff + c, f32w) : 0.f;
#pragma unroll
            for (int r = 0; r < 4; ++r) {
                int row = bm + wm * 64 + mi * 16 + (lane >> 4) * 4 + r;
                float v = acc[mi][nj][r] + bia;
                if (ACT == 1) v = 0.5f * v * (1.0f + erff(v * 0.70710678118654752f));
                if (OUTM == 0) {
                    if (ACCUM) v += tof(C[(size_t)row * N + c]);
                    storev(C + (size_t)row * N + c, v);
                } else {
                    ST[(size_t)row * CD + c] = v;
                }
            }
        }
    }
}

// ---------------------------------------------------------------------------
// RoPE (in-place, bf16) on q and k + LDS-tiled transpose of v -> vt.
// PROVEN rounds 12-30.
// ---------------------------------------------------------------------------
__global__ __launch_bounds__(256) void ropeV_kernel(
    bf16* __restrict__ q, bf16* __restrict__ k,
    const bf16* __restrict__ v, bf16* __restrict__ vt)
{
    int t0 = blockIdx.x * 64, hh = blockIdx.y, b = blockIdx.z;
    int tid = threadIdx.x;
    __shared__ short lt[64][72];
    int c = tid & 63;
    int r0 = tid >> 6;
    int ip = c >> 1;
    float inv = powf(10000.f, -(float)(2 * ip) / 64.f);
#pragma unroll
    for (int i = 0; i < 16; ++i) {
        int r = r0 + i * 4;
        int t = t0 + r;
        size_t idx = ((size_t)b * CT + t) * 512 + hh * 64 + c;
        float qv = tof(q[idx]);
        float kv = tof(k[idx]);
        float ang = (float)t * inv;
        float sn, cs;
        sincosf(ang, &sn, &cs);
        float qp = __shfl_xor(qv, 1);
        float kp = __shfl_xor(kv, 1);
        float rq, rk;
        if (c & 1) { rq = qp * sn + qv * cs; rk = kp * sn + kv * cs; }
        else       { rq = qv * cs - qp * sn; rk = kv * cs - kp * sn; }
        q[idx] = __float2bfloat16(rq);
        k[idx] = __float2bfloat16(rk);
        lt[r][c] = ((const short*)v)[idx];
    }
    __syncthreads();
#pragma unroll
    for (int i = 0; i < 16; ++i) {
        int c2 = r0 + i * 4;
        int r2 = c;
        ((short*)vt)[((size_t)(b * CH + hh) * 64 + c2) * CT + t0 + r2] = lt[r2][c2];
    }
}

// ---------------------------------------------------------------------------
// MFMA flash attention (core PROVEN rounds 12-30).
// FUSE=1: grid x=10; epilogue proj1+RoPE -> q1/k1/v1t.
// FUSE=0: grid x=9; tiles 1..8 -> o1mid (batch-major), tile-9 -> o1s.
// ---------------------------------------------------------------------------
template <int FUSE>
__global__ __launch_bounds__(256) void attn_mfma(
    const bf16* __restrict__ q, const bf16* __restrict__ k, const bf16* __restrict__ vt,
    bf16* __restrict__ o,
    int qsb, int qsh, int qst,
    int ksb, int ksh, int kst,
    int seg,
    const bf16* __restrict__ Wq1t, const bf16* __restrict__ Wk1t, const bf16* __restrict__ Wv1t,
    bf16* __restrict__ q1o, bf16* __restrict__ k1o, bf16* __restrict__ v1to)
{
    const int tid = threadIdx.x;
    const int lane = tid & 63;
    const int wrow = tid >> 6;
    const int hh = blockIdx.y, b = blockIdx.z;
    const int qbase = (FUSE ? ((int)gridDim.x - 1 - (int)blockIdx.x)
                            : ((int)gridDim.x - (int)blockIdx.x)) * 64;

    __shared__ __align__(16) short Qs[64 * LP];
    __shared__ __align__(16) short Ks[64 * LP];
    __shared__ __align__(16) short Vs[64 * LP];
    __shared__ __align__(16) short Ps[64 * LP];

    const size_t qb0 = (size_t)b * qsb + (size_t)hh * qsh;
    const size_t kb0 = (size_t)b * ksb + (size_t)hh * ksh;
    const size_t vtb = (size_t)(b * CH + hh) * 64 * CT;

    int srow[2], skc[2], soff[2];
#pragma unroll
    for (int i = 0; i < 2; ++i) {
        int c = i * 256 + tid;
        srow[i] = c >> 3;
        skc[i] = c & 7;
        soff[i] = srow[i] * LP + skc[i] * 8;
    }

    bf16x8 rQ[2], rK[2], rV[2];
#pragma unroll
    for (int i = 0; i < 2; ++i) {
        rQ[i] = *(const bf16x8*)(q + qb0 + (size_t)(qbase + srow[i]) * qst + skc[i] * 8);
        rK[i] = *(const bf16x8*)(k + kb0 + (size_t)srow[i] * kst + skc[i] * 8);
        rV[i] = *(const bf16x8*)(vt + vtb + (size_t)srow[i] * CT + skc[i] * 8);
    }

    float mrow[4], lrow[4];
    f32x4 oacc[4];
#pragma unroll
    for (int r = 0; r < 4; ++r) { mrow[r] = -1e30f; lrow[r] = 0.f; }
#pragma unroll
    for (int nd = 0; nd < 4; ++nd) oacc[nd] = (f32x4){0.f, 0.f, 0.f, 0.f};

    const int ntiles = qbase / 64 + 1;
    for (int ti = 0; ti < ntiles; ++ti) {
        __syncthreads();
        if (ti == 0) {
#pragma unroll
            for (int i = 0; i < 2; ++i) *(bf16x8*)&Qs[soff[i]] = rQ[i];
        }
#pragma unroll
        for (int i = 0; i < 2; ++i) {
            *(bf16x8*)&Ks[soff[i]] = rK[i];
            *(bf16x8*)&Vs[soff[i]] = rV[i];
        }
        if (ti + 1 < ntiles) {
            int j1 = (ti + 1) * 64;
#pragma unroll
            for (int i = 0; i < 2; ++i) {
                rK[i] = *(const bf16x8*)(k + kb0 + (size_t)(j1 + srow[i]) * kst + skc[i] * 8);
                rV[i] = *(const bf16x8*)(vt + vtb + (size_t)srow[i] * CT + j1 + skc[i] * 8);
            }
        }
        __syncthreads();

        f32x4 sacc[4];
#pragma unroll
        for (int nj = 0; nj < 4; ++nj) sacc[nj] = (f32x4){0.f, 0.f, 0.f, 0.f};
#pragma unroll
        for (int kh = 0; kh < 2; ++kh) {
            int cl = kh * 4 + (lane >> 4);
            bf16x8 av = *(const bf16x8*)&Qs[(wrow * 16 + (lane & 15)) * LP + cl * 8];
#pragma unroll
            for (int nj = 0; nj < 4; ++nj) {
                bf16x8 bv = *(const bf16x8*)&Ks[(nj * 16 + (lane & 15)) * LP + cl * 8];
                sacc[nj] = __builtin_amdgcn_mfma_f32_16x16x32_bf16(av, bv, sacc[nj], 0, 0, 0);
            }
        }

        const bool diag = (ti == ntiles - 1);
        float pm[4] = {-1e30f, -1e30f, -1e30f, -1e30f};
#pragma unroll
        for (int nj = 0; nj < 4; ++nj) {
            int col_l = nj * 16 + (lane & 15);
#pragma unroll
            for (int r = 0; r < 4; ++r) {
                int row_l = wrow * 16 + ((lane >> 4) << 2) + r;
                float s = (diag && col_l > row_l) ? -1e30f : sacc[nj][r] * 0.125f;
                sacc[nj][r] = s;
                pm[r] = fmaxf(pm[r], s);
            }
        }
#pragma unroll
        for (int msk = 1; msk < 16; msk <<= 1)
#pragma unroll
            for (int r = 0; r < 4; ++r) pm[r] = fmaxf(pm[r], __shfl_xor(pm[r], msk));

        float corr[4], rs[4] = {0.f, 0.f, 0.f, 0.f};
#pragma unroll
        for (int r = 0; r < 4; ++r) {
            float mn = fmaxf(mrow[r], pm[r]);
            corr[r] = __expf(mrow[r] - mn);
            mrow[r] = mn;
        }
#pragma unroll
        for (int nj = 0; nj < 4; ++nj)
#pragma unroll
            for (int r = 0; r < 4; ++r) {
                float p = __expf(sacc[nj][r] - mrow[r]);
                sacc[nj][r] = p;
                rs[r] += p;
            }
#pragma unroll
        for (int msk = 1; msk < 16; msk <<= 1)
#pragma unroll
            for (int r = 0; r < 4; ++r) rs[r] += __shfl_xor(rs[r], msk);
#pragma unroll
        for (int r = 0; r < 4; ++r) lrow[r] = lrow[r] * corr[r] + rs[r];
#pragma unroll
        for (int nd = 0; nd < 4; ++nd)
#pragma unroll
            for (int r = 0; r < 4; ++r) oacc[nd][r] *= corr[r];

#pragma unroll
        for (int nj = 0; nj < 4; ++nj)
#pragma unroll
            for (int r = 0; r < 4; ++r) {
                bf16 pb = __float2bfloat16(sacc[nj][r]);
                Ps[(wrow * 16 + ((lane >> 4) << 2) + r) * LP + nj * 16 + (lane & 15)] =
                    *(short*)&pb;
            }

#pragma unroll
        for (int kh = 0; kh < 2; ++kh) {
            int cl = kh * 4 + (lane >> 4);
            bf16x8 pa = *(const bf16x8*)&Ps[(wrow * 16 + (lane & 15)) * LP + cl * 8];
#pragma unroll
            for (int nd = 0; nd < 4; ++nd) {
                bf16x8 bv = *(const bf16x8*)&Vs[(nd * 16 + (lane & 15)) * LP + cl * 8];
                oacc[nd] = __builtin_amdgcn_mfma_f32_16x16x32_bf16(pa, bv, oacc[nd], 0, 0, 0);
            }
        }
    }

    if (FUSE == 0) {
        // per-block-uniform destination select (tile granularity == 64)
        bf16* dst;
        int rbase;
        if (qbase == 576) { dst = q1o; rbase = b * 64 - 576; }          // o1s
        else              { dst = o;   rbase = (b * 8 + seg) * 512 - 64; }  // o1mid
#pragma unroll
        for (int nd = 0; nd < 4; ++nd) {
#pragma unroll
            for (int r = 0; r < 4; ++r) {
                int row_g = qbase + wrow * 16 + ((lane >> 4) << 2) + r;
                int col = nd * 16 + (lane & 15);
                dst[(size_t)(rbase + row_g) * 512 + hh * 64 + col] =
                    __float2bfloat16(oacc[nd][r] / lrow[r]);
            }
        }
    } else {
#pragma unroll
        for (int nd = 0; nd < 4; ++nd)
#pragma unroll
            for (int r = 0; r < 4; ++r) {
                int row_l = wrow * 16 + ((lane >> 4) << 2) + r;
                bf16 ob16 = __float2bfloat16(oacc[nd][r] / lrow[r]);
                Qs[row_l * LP + nd * 16 + (lane & 15)] = *(short*)&ob16;
            }
        __syncthreads();

        const size_t whb = (size_t)hh * 4096;
        f32x4 qa[4], ka[4], va[4];
#pragma unroll
        for (int nj = 0; nj < 4; ++nj) {
            qa[nj] = (f32x4){0.f, 0.f, 0.f, 0.f};
            ka[nj] = (f32x4){0.f, 0.f, 0.f, 0.f};
            va[nj] = (f32x4){0.f, 0.f, 0.f, 0.f};
        }
#pragma unroll
        for (int kh = 0; kh < 2; ++kh) {
            int cl = kh * 4 + (lane >> 4);
            bf16x8 av = *(const bf16x8*)&Qs[(wrow * 16 + (lane & 15)) * LP + cl * 8];
#pragma unroll
            for (int nj = 0; nj < 4; ++nj) {
                int rowb = nj * 16 + (lane & 15);
                bf16x8 bq = *(const bf16x8*)(Wq1t + whb + (size_t)rowb * 64 + cl * 8);
                bf16x8 bk = *(const bf16x8*)(Wk1t + whb + (size_t)rowb * 64 + cl * 8);
                bf16x8 bw = *(const bf16x8*)(Wv1t + whb + (size_t)rowb * 64 + cl * 8);
                qa[nj] = __builtin_amdgcn_mfma_f32_16x16x32_bf16(av, bq, qa[nj], 0, 0, 0);
                ka[nj] = __builtin_amdgcn_mfma_f32_16x16x32_bf16(av, bk, ka[nj], 0, 0, 0);
                va[nj] = __builtin_amdgcn_mfma_f32_16x16x32_bf16(av, bw, va[nj], 0, 0, 0);
            }
        }
        const size_t bh = (size_t)(b * CH + hh);
#pragma unroll
        for (int nj = 0; nj < 4; ++nj) {
            int col = nj * 16 + (lane & 15);
            int ip = col >> 1;
            float inv = powf(10000.f, -(float)(2 * ip) / 64.f);
#pragma unroll
            for (int r = 0; r < 4; ++r) {
                int row_l = wrow * 16 + ((lane >> 4) << 2) + r;
                int t = qbase + row_l;
                float ang = (float)t * inv;
                float sn, cs;
                sincosf(ang, &sn, &cs);
                float aq = qa[nj][r], ak = ka[nj][r];
                float pq = __shfl_xor(aq, 1);
                float pk = __shfl_xor(ak, 1);
                float rq, rk;
                if (col & 1) { rq = pq * sn + aq * cs; rk = pk * sn + ak * cs; }
                else         { rq = aq * cs - pq * sn; rk = ak * cs - pk * sn; }
                size_t roff = (bh * CT + t) * 64 + col;
                q1o[roff] = __float2bfloat16(rq);
                k1o[roff] = __float2bfloat16(rk);
                v1to[(bh * 64 + col) * CT + t] = __float2bfloat16(va[nj][r]);
            }
        }
    }
}

// toks = concat([state, x_seg, state]) -> bf16 (PROVEN; separate pass wins)
__global__ __launch_bounds__(256) void build_toks_kernel(
    const void* __restrict__ x, const float* __restrict__ state, bf16* __restrict__ toks,
    int seg, const int* __restrict__ flag)
{
    const int f32w = flag[0];
    int idx = blockIdx.x * 256 + threadIdx.x;  // B*T*D
    int d = idx & (CD - 1);
    int t = (idx >> 10) % CT;
    int b = idx / (CT * CD);
    float v;
    if (t < CST) v = state[(b * CST + t) * CD + d];
    else if (t < CST + CL) v = ldin(x, ((size_t)b * CS + seg * CL + (t - CST)) * CD + d, f32w);
    else v = state[(b * CST + (t - CST - CL)) * CD + d];
    toks[idx] = __float2bfloat16(v);
}

__global__ __launch_bounds__(256) void init_state_kernel(
    const void* __restrict__ s0, float* __restrict__ state, const int* __restrict__ flag)
{
    const int f32w = flag[0];
    int idx = blockIdx.x * 256 + threadIdx.x;  // B*ST*D
    state[idx] = ldin(s0, idx % (CST * CD), f32w);
}

// LayerNorm(ra + x) * g + b.  ra bf16 (PROVEN round 27).
__global__ __launch_bounds__(256) void ln_kernel(
    const bf16* __restrict__ ra, const void* __restrict__ x,
    const void* __restrict__ g, const void* __restrict__ bb,
    void* __restrict__ outp, int out_ext, const int* __restrict__ flag)
{
    const int f32w = flag[0];
    int row = blockIdx.x;
    int tid = threadIdx.x;
    __shared__ float buf[CD];
    __shared__ float red[4];

    float s = 0.f;
    for (int c = tid; c < CD; c += 256) {
        float v = tof(ra[(size_t)row * CD + c]) + ldin(x, (size_t)row * CD + c, f32w);
        buf[c] = v;
        s += v;
    }
#pragma unroll
    for (int off = 32; off; off >>= 1) s += __shfl_xor(s, off);
    if ((tid & 63) == 0) red[tid >> 6] = s;
    __syncthreads();
    float mu = (red[0] + red[1] + red[2] + red[3]) * (1.f / CD);
    __syncthreads();

    float vs = 0.f;
    for (int c = tid; c < CD; c += 256) {
        float d0 = buf[c] - mu;
        vs += d0 * d0;
    }
#pragma unroll
    for (int off = 32; off; off >>= 1) vs += __shfl_xor(vs, off);
    if ((tid & 63) == 0) red[tid >> 6] = vs;
    __syncthreads();
    float var = (red[0] + red[1] + red[2] + red[3]) * (1.f / CD);
    float rs = rsqrtf(var + 1e-5f);

    for (int c = tid; c < CD; c += 256) {
        float y = (buf[c] - mu) * rs * ldin(g, c, f32w) + ldin(bb, c, f32w);
        size_t idx = (size_t)row * CD + c;
        if (!out_ext) {
            ((bf16*)outp)[idx] = __float2bfloat16(y);
        } else if (f32w) {
            ((float*)outp)[idx] = y;
        } else {
            ((bf16*)outp)[idx] = __float2bfloat16(y);
        }
    }
}

extern "C" void kernel_launch(void* const* d_in, const int* in_sizes, int n_in,
                              void* d_out, int out_size, void* d_ws, size_t ws_size,
                              hipStream_t stream)
{
    const void* x      = d_in[0];
    const void* s0     = d_in[1];
    const void* Wq0    = d_in[2];
    const void* Wk0    = d_in[3];
    const void* Wv0    = d_in[4];
    const void* Wq1    = d_in[5];
    const void* Wk1    = d_in[6];
    const void* Wv1    = d_in[7];
    const void* Wo     = d_in[8];
    const void* bo     = d_in[9];
    const void* g_attn = d_in[10];
    const void* b_attn = d_in[11];
    const void* W1     = d_in[12];
    const void* b1     = d_in[13];
    const void* W2     = d_in[14];
    const void* b2     = d_in[15];
    const void* g_mlp  = d_in[16];
    const void* b_mlp  = d_in[17];

    // workspace slot layout BYTE-IDENTICAL to passing rounds 2/6-30 (~90.7 MB)
    int* flag = (int*)d_ws;
    float* f = (float*)((char*)d_ws + 16);
    float* toks_slot = f; f += (size_t)CB * CT * CD;       // bf16 toks
    float* q0_slot = f;  f += (size_t)CB * CH * CT * 64;   // bf16 q0 [1280][512]
    float* k0_slot = f;  f += (size_t)CB * CH * CT * 64;   // bf16 k0
    float* v0_slot = f;  f += (size_t)CB * CH * CT * 64;   // bf16 v0
    float* o0_slot = f;  f += (size_t)CB * CH * CT * 64;   // bf16 v0t
    float* q1_slot = f;  f += (size_t)CB * CH * CT * 64;   // bf16 q1
    float* k1_slot = f;  f += (size_t)CB * CH * CT * 64;   // bf16 k1
    float* v1_slot = f;  f += (size_t)CB * CH * CT * 64;   // bf16 v1t
    float* o1t_slot = f; f += (size_t)CB * CT * (CH * 64); // (unused during segments)
    float* seg_slot = f; f += (size_t)CB * CT * CD;        // (unused during segments)
    float* state = f;   f += (size_t)CB * CST * CD;        // fp32 state
    float* a_slot = f;  f += (size_t)CB * CS * CD;         // bf16 a (half used)
    bf16* h = (bf16*)f;                                    // LN1 out [B*S, D] bf16
    bf16* tail = h + (size_t)CB * CS * CD;                 // 8.39 MB tail slot

    bf16* toks = (bf16*)toks_slot;
    bf16* q0b = (bf16*)q0_slot;
    bf16* k0b = (bf16*)k0_slot;
    bf16* v0b = (bf16*)v0_slot;
    bf16* v0t = (bf16*)o0_slot;
    bf16* q1b = (bf16*)q1_slot;
    bf16* k1b = (bf16*)k1_slot;
    bf16* v1t = (bf16*)v1_slot;
    bf16* ab  = (bf16*)a_slot;                             // [8192][1024] bf16
    bf16* WtQ = h;                                         // h region dead until LN1
    bf16* WtK = WtQ + (size_t)512 * 1024;
    bf16* WtV = WtK + (size_t)512 * 1024;
    bf16* WtO = WtV + (size_t)512 * 1024;                  // [1024][512]
    bf16* WtQ1 = WtO + (size_t)1024 * 512;                 // per-head [8][64][64]
    bf16* WtK1 = WtQ1 + (size_t)8 * 4096;
    bf16* WtV1 = WtK1 + (size_t)8 * 4096;
    // o1mid/o1s after transposed weights in h region (round-26/27-proven fit).
    bf16* o1mid = WtV1 + (size_t)8 * 4096;                 // [B*NSEG*512][512]
    bf16* o1s = o1mid + (size_t)CB * NSEG * 512 * 512;     // [128][512]
    // MLP phase (toks..q1 region dead): g1 at region base, Wt1 after, Wt2 tail.
    bf16* g1  = (bf16*)toks_slot;                          // [8192][1024] 16.78 MB
    bf16* Wt1 = g1 + (size_t)CB * CS * CD;                 // [CDH][CD]    8.39 MB
    bf16* Wt2 = tail;                                      // [CD][CDH]    8.39 MB

    sniff_kernel<<<1, 64, 0, stream>>>(x, flag);
    init_state_kernel<<<(CB * CST * CD) / 256, 256, 0, stream>>>(s0, state, flag);

    transpose3_kernel<<<dim3(8, 16, 3), 256, 0, stream>>>(
        Wq0, Wk0, Wv0, WtQ, WtK, WtV, flag);
    transpose_kernel<<<dim3(16, 8), 256, 0, stream>>>(Wo, WtO, 512, CD, flag);
    transposeH_kernel<<<24, 256, 0, stream>>>(Wq1, Wk1, Wv1, WtQ1, WtK1, WtV1, flag);
    // W2 transpose at startup (PROVEN round 28): overlaps the segment loop.
    transpose_kernel<<<dim3(CD / 64, CDH / 64), 256, 0, stream>>>(W2, Wt2, CDH, CD, flag);

    for (int seg = 0; seg < NSEG; ++seg) {
        build_toks_kernel<<<(CB * CT * CD) / 256, 256, 0, stream>>>(x, state, toks, seg, flag);
        // QKV GEMM: LOW-OCC (120 blocks) -> reg-staged template (round-29 best)
        mfma_reg<bf16, 0, 0, 0><<<dim3(10, 4, 3), 256, 0, stream>>>(
            toks, WtQ, WtK, WtV, q0b, k0b, v0b, nullptr, nullptr, 0,
            CB * CT, 512, CD, CD, CD, 0, flag);
        // RoPE q0,k0 in place + V transpose -> v0t (proven separate pass)
        ropeV_kernel<<<dim3(CT / 64, CH, CB), 256, 0, stream>>>(q0b, k0b, v0b, v0t);
        // attn1 (row-major Q/K + v0t) with FUSED proj1+RoPE epilogue (grid 10)
        attn_mfma<1><<<dim3(CT / 64, CH, CB), 256, 0, stream>>>(
            q0b, k0b, v0t, nullptr,
            CT * 512, 64, 512,
            CT * 512, 64, 512,
            seg,
            WtQ1, WtK1, WtV1, q1b, k1b, v1t);
        // attn2 (head-major Q/K + v1t), grid 9: middle -> o1mid, tile9 -> o1s
        attn_mfma<0><<<dim3(9, CH, CB), 256, 0, stream>>>(
            q1b, k1b, v1t, o1mid,
            CH * CT * 64, CT * 64, 64,
            CH * CT * 64, CT * 64, 64,
            seg,
            nullptr, nullptr, nullptr, o1s, nullptr, nullptr);
        // small Wo: LOW-OCC (8 blocks) -> reg-staged template
        mfma_reg<bf16, 0, 2, 0><<<dim3(1, 8, 1), 256, 0, stream>>>(
            o1s, WtO, WtO, WtO, ab, ab, ab, state, bo, 0,
            128, CD, 512, 512, 512, seg, flag);
    }

    // big Wo: HIGH-OCC (512 blocks) -> gload_lds template (round-30 best)
    mfma_glds<bf16, 0, 0, 0><<<dim3(64, 8, 1), 256, 0, stream>>>(
        o1mid, WtO, WtO, WtO, ab, ab, ab, nullptr, bo, 0,
        CB * CS, CD, 512, 512, 512, 0, flag);

    // h = LN(ab + x) -> bf16 internal (overwrites WtQ..o1s — dead by now)
    ln_kernel<<<CB * CS, 256, 0, stream>>>(ab, x, g_attn, b_attn, h, 0, flag);

    transpose_kernel<<<dim3(CDH / 64, CD / 64), 256, 0, stream>>>(W1, Wt1, CD, CDH, flag);

    // MLP chunked over the hidden dim; HIGH-OCC (512 blocks) -> gload_lds
    for (int c = 0; c < 4; ++c) {
        mfma_glds<bf16, 1, 0, 0><<<dim3(64, 8, 1), 256, 0, stream>>>(
            h, Wt1 + (size_t)c * 1024 * CD, Wt1, Wt1, g1, g1, g1, nullptr,
            b1, c * 1024, CB * CS, 1024, CD, CD, CD, 0, flag);
        if (c == 0)
            mfma_glds<bf16, 0, 0, 0><<<dim3(64, 8, 1), 256, 0, stream>>>(
                g1, Wt2 + (size_t)c * 1024, Wt2, Wt2, ab, ab, ab, nullptr,
                b2, 0, CB * CS, CD, 1024, 1024, CDH, 0, flag);
        else
            mfma_glds<bf16, 0, 0, 1><<<dim3(64, 8, 1), 256, 0, stream>>>(
                g1, Wt2 + (size_t)c * 1024, Wt2, Wt2, ab, ab, ab, nullptr,
                nullptr, 0, CB * CS, CD, 1024, 1024, CDH, 0, flag);
    }
    ln_kernel<<<CB * CS, 256, 0, stream>>>(ab, x, g_mlp, b_mlp, d_out, 1, flag);
}